// Round 12
// baseline (762.680 us; speedup 1.0000x reference)
//
#include <hip/hip_runtime.h>
#include <stdint.h>

#define NEGF (-1.0e8f)
#define NCELL (512 * 512)
#define INVLN2 1.4426950408889634f
#define NIV 39  // intervals of 32 diagonals; skew 32/wave-stage

// raw barrier: LDS ordering only (never drains vmcnt -> global ops stay in flight)
#define BAR() asm volatile("s_waitcnt lgkmcnt(0)\n\ts_barrier" ::: "memory")

#define REP32(X) X(0) X(1) X(2) X(3) X(4) X(5) X(6) X(7) X(8) X(9) X(10) X(11) X(12) X(13) X(14) X(15) \
                 X(16) X(17) X(18) X(19) X(20) X(21) X(22) X(23) X(24) X(25) X(26) X(27) X(28) X(29) X(30) X(31)
#define REP33(X) REP32(X) X(32)
#define LIST1_32(X) X(1) X(2) X(3) X(4) X(5) X(6) X(7) X(8) X(9) X(10) X(11) X(12) X(13) X(14) X(15) X(16) \
                    X(17) X(18) X(19) X(20) X(21) X(22) X(23) X(24) X(25) X(26) X(27) X(28) X(29) X(30) X(31) X(32)

__device__ __forceinline__ float exp2f_(float x) {
#if __has_builtin(__builtin_amdgcn_exp2f)
  return __builtin_amdgcn_exp2f(x);
#else
  return exp2f(x);
#endif
}
__device__ __forceinline__ float log2f_(float x) {
#if __has_builtin(__builtin_amdgcn_logf)
  return __builtin_amdgcn_logf(x);
#else
  return log2f(x);
#endif
}
__device__ __forceinline__ uint32_t pknorm16(float a, float b) {
#if __has_builtin(__builtin_amdgcn_cvt_pknorm_u16)
  typedef unsigned short u2v __attribute__((ext_vector_type(2)));
  union { u2v v; uint32_t u; } cv;
  cv.v = __builtin_amdgcn_cvt_pknorm_u16(a, b);
  return cv.u;
#else
  uint32_t pa = (uint32_t)(a * 65535.0f + 0.5f);
  uint32_t pb = (uint32_t)(b * 65535.0f + 0.5f);
  return pa | (pb << 16);
#endif
}

// DPP wave shifts: 0x138 wave_shr:1 (lane l <- l-1, lane0 <- old), 0x130 wave_shl:1 (lane l <- l+1, lane63 <- old)
__device__ __forceinline__ float dpp_shr1_f(float src, float old0) {
  return __int_as_float(__builtin_amdgcn_update_dpp(
      __float_as_int(old0), __float_as_int(src), 0x138, 0xF, 0xF, false));
}
__device__ __forceinline__ float dpp_shl1_f(float src, float old63) {
  return __int_as_float(__builtin_amdgcn_update_dpp(
      __float_as_int(old63), __float_as_int(src), 0x130, 0xF, 0xF, false));
}
__device__ __forceinline__ uint32_t dpp_shl1_u(uint32_t src, uint32_t old63) {
  return (uint32_t)__builtin_amdgcn_update_dpp((int)old63, (int)src, 0x130, 0xF, 0xF, false);
}

// offset of diagonal d; lo(d)=max(1,d-512)
__device__ __forceinline__ int offd(int d) {
  return (d <= 513) ? (((d - 2) * (d - 1)) >> 1)
                    : (NCELL - (((1025 - d) * (1026 - d)) >> 1));
}
__device__ __forceinline__ int dbase(int d) {
  const int lo = (d > 513) ? d - 512 : 1;
  return offd(d) - lo;
}

// forward softmax-LSE cell (base-2 domain)
__device__ __forceinline__ void fcell(float& nv, uint32_t& pk, float dg, float up0,
                                      float lf0, float th, float A2) {
  float up = up0 + A2, lf = lf0 + A2;
  float mx = fmaxf(fmaxf(dg, up), lf);
  float ed = exp2f_(dg - mx), eu = exp2f_(up - mx), el = exp2f_(lf - mx);
  float s = ed + eu + el;
  nv = th + mx + log2f_(s);
  float rs = __builtin_amdgcn_rcpf(s);
  pk = pknorm16(ed * rs, eu * rs);
}

// ---------------------------------------------------------------------------
// K1: T[22][512] = W_embed @ W_proj + b_proj
// ---------------------------------------------------------------------------
__global__ void k_T(const float* __restrict__ We, const float* __restrict__ Wp,
                    const float* __restrict__ bp, float* __restrict__ T) {
  int a = blockIdx.x, c = threadIdx.x;
  __shared__ float e[512];
  e[c] = We[a * 512 + c];
  __syncthreads();
  float acc = bp[c];
#pragma unroll 8
  for (int k = 0; k < 512; ++k) acc = fmaf(e[k], Wp[k * 512 + c], acc);
  T[a * 512 + c] = acc;
}

// ---------------------------------------------------------------------------
// K2: G2[a][a2] (stride 37 for LDS bank spread) = (T T^T)/ln2 ; u,v gap LUTs
// ---------------------------------------------------------------------------
__global__ void k_G(const float* __restrict__ T, const float* __restrict__ Wg,
                    float* __restrict__ G, float* __restrict__ u, float* __restrict__ v) {
  __shared__ float Ts[22 * 516];
  for (int k = threadIdx.x; k < 22 * 512; k += 512) {
    int a = k >> 9, c = k & 511;
    Ts[a * 516 + c] = T[k];
  }
  __syncthreads();
  for (int idx = threadIdx.x; idx < 528; idx += 512) {
    float s = 0.f;
    if (idx < 484) {
      int a = idx / 22, a2 = idx - 22 * a;
      const float* pa = &Ts[a * 516];
      const float* pb = &Ts[a2 * 516];
      for (int c = 0; c < 512; ++c) s = fmaf(pa[c], pb[c], s);
      G[a * 37 + a2] = s * INVLN2;  // padded row stride 37
    } else if (idx < 506) {
      int a = idx - 484;
      const float* pa = &Ts[a * 516];
      for (int c = 0; c < 512; ++c) s = fmaf(pa[c], Wg[c], s);
      u[a] = s;
    } else {
      int a = idx - 506;
      const float* pa = &Ts[a * 516];
      for (int c = 0; c < 512; ++c) s = fmaf(pa[c], Wg[512 + c], s);
      v[a] = s;
    }
  }
}

// ---------------------------------------------------------------------------
// K3: A2[b]
// ---------------------------------------------------------------------------
__global__ void k_A(const int* __restrict__ x, const int* __restrict__ y,
                    const float* __restrict__ u, const float* __restrict__ v,
                    const float* __restrict__ bg, float* __restrict__ A) {
  int b = blockIdx.x, t = threadIdx.x;
  const int* xb = x + b * 512;
  const int* yb = y + b * 512;
  float s = u[xb[t]] + u[xb[t + 256]] + v[yb[t]] + v[yb[t + 256]];
  for (int o = 32; o > 0; o >>= 1) s += __shfl_down(s, o, 64);
  __shared__ float w[4];
  if ((t & 63) == 0) w[t >> 6] = s;
  __syncthreads();
  if (t == 0) A[b] = ((w[0] + w[1] + w[2] + w[3]) * (1.0f / 512.0f) + bg[0]) * INVLN2;
}

// ---------------------------------------------------------------------------
// K4: skewed 8-stage pipeline DP, 2 BATCHES PER BLOCK (16 waves, 4/SIMD).
//     waves 0-7 -> batch 2*blockIdx, waves 8-15 -> batch 2*blockIdx+1.
//     1 row/lane (r=64*wl+lane+1), KD=32, mod-128 rings, reg ys prefetch.
// ---------------------------------------------------------------------------
__global__ __launch_bounds__(1024) void k_nw(const int* __restrict__ x, const int* __restrict__ y,
                                             const float* __restrict__ G,
                                             const float* __restrict__ Aarr,
                                             uint32_t* __restrict__ po,
                                             float* __restrict__ ews) {
  const int tid = threadIdx.x;
  const int w = __builtin_amdgcn_readfirstlane(tid) >> 6;  // 0..15, forced SGPR
  const int wb = w >> 3;  // batch slot within pair
  const int wl = w & 7;   // pipeline stage
  const int lane = tid & 63;
  __shared__ float Gl[814];          // 22 x 37 (shared by both batches)
  __shared__ int ysPad[2][960];      // per batch: zeros [0,320), ys [320,832), zeros [832,960)
  __shared__ float Vring[2][8][256];     // mod-128 double-write
  __shared__ float Ering[2][8][256];
  __shared__ uint32_t Pring[2][8][256];

  const int b = blockIdx.x * 2 + wb;
  const int* xbp = x + b * 512;
  // ysPad fill: threads [0,512) handle batch slot 0, [512,1024) slot 1
  const int ht = tid & 511, hb = tid >> 9;
  const int* yfill = y + (blockIdx.x * 2 + hb) * 512;
  if (ht < 320) ysPad[hb][ht] = 0;
  if (ht >= 384) ysPad[hb][ht + 448] = 0;  // covers [832, 960)
  ysPad[hb][320 + ht] = yfill[ht];
  for (int k = tid; k < 814; k += 1024) Gl[k] = G[k];
  for (int k = tid; k < 4096; k += 1024) {
    ((float*)Vring)[k] = NEGF;
    ((float*)Ering)[k] = 0.0f;
    ((uint32_t*)Pring)[k] = 0u;
  }
  const float A2 = Aarr[b];
  const int r = 64 * wl + lane + 1;
  const int xr = xbp[r - 1] * 37;
  const bool lane0 = (lane == 0), lane63 = (lane == 63);
  const bool wgt0 = (wl > 0), wlt7 = (wl < 7);
  const bool rless = (r < 512);
  po += (size_t)b * NCELL;
  ews += (size_t)b * NCELL;
  __syncthreads();

  // ================= forward =================
  const int ivLoF = 2 * wl;
  const int ivHiF = (3 * wl + 17 < NIV - 1) ? 3 * wl + 17 : NIV - 1;
  const int dnP0 = 2 + 32 * wl;  // dn0 at ivLoF

#define DECLTH(m) float th##m;
  REP32(DECLTH)
#define DECLYA(m) int ya##m;
  REP32(DECLYA)
#define PROTH(m) { const int ix = (dnP0 + (m)) + 319 - r; th##m = Gl[xr + ysPad[wb][ix]]; }
  REP32(PROTH)

  float va = NEGF, rupP = NEGF;
#pragma unroll 1
  for (int iv = 0; iv < NIV; ++iv) {
    if (iv >= ivLoF && iv <= ivHiF) {
      const int dn0 = 2 - 32 * wl + 32 * iv;  // scalar
      // batch-load next interval's ys values into registers (stride-1, conflict-free)
      const int iya = dn0 + 351 - r;  // (dn0+32) - 1 - r + 320
#define LYA(m) ya##m = ysPad[wb][iya + (m)];
      REP32(LYA)
      // ring prefetch (broadcast reads)
      const float* VrB = &Vring[wb][wl][(dn0 - 1) & 127];
#define DECLRV(k) float rv##k = VrB[(k) - 1];
      LIST1_32(DECLRV)

#define FSTEP(m, k) { \
    const int dn = dn0 + (m); \
    float rdg = rupP; \
    if ((m) == 0 && wl == 0 && iv == 0) rdg = lane0 ? 0.0f : rdg; /* V[0,0]=0 corner */ \
    const float rup = dpp_shr1_f(va, rv##k); \
    float nv; uint32_t pk; \
    fcell(nv, pk, rdg, rup, va, th##m, A2); \
    const bool vv = (unsigned)(dn - r - 1) < 512u; \
    nv = vv ? nv : NEGF; \
    if (vv) po[dbase(dn) + r] = pk; \
    if (wlt7 && lane63) { const int sl = dn & 127; Vring[wb][wl + 1][sl] = nv; Vring[wb][wl + 1][sl + 128] = nv; } \
    th##m = Gl[xr + ya##m]; /* refill for next interval, reg-ready address */ \
    va = nv; rupP = rup; \
  }
      FSTEP(0, 1)  FSTEP(1, 2)  FSTEP(2, 3)  FSTEP(3, 4)  FSTEP(4, 5)  FSTEP(5, 6)  FSTEP(6, 7)  FSTEP(7, 8)
      FSTEP(8, 9)  FSTEP(9, 10) FSTEP(10, 11) FSTEP(11, 12) FSTEP(12, 13) FSTEP(13, 14) FSTEP(14, 15) FSTEP(15, 16)
      FSTEP(16, 17) FSTEP(17, 18) FSTEP(18, 19) FSTEP(19, 20) FSTEP(20, 21) FSTEP(21, 22) FSTEP(22, 23) FSTEP(23, 24)
      FSTEP(24, 25) FSTEP(25, 26) FSTEP(26, 27) FSTEP(27, 28) FSTEP(28, 29) FSTEP(29, 30) FSTEP(30, 31) FSTEP(31, 32)
    }
    BAR();
  }

  // ================= transition: drain p stores once =================
  asm volatile("s_waitcnt vmcnt(0)" ::: "memory");
  __threadfence_block();
  __syncthreads();

  // ================= backward =================
  const float inv16 = 1.0f / 65535.0f;
  const bool w7 = (wl == 7);
  const int ivLoB = 14 - 2 * wl;
  const int ivHiB = 38 - 3 * wl;
  float ea = (w7 && lane63) ? 1.0f : 0.0f;
  float reaP = 0.0f;
  uint32_t rqP = 0u;
  if (w7 && lane63) ews[NCELL - 1] = 1.0f;  // E(512,512) seed (diag 1024)

#define DECLQ(k) uint32_t q##k, qn##k;
  REP33(DECLQ)
  {
    const int t0p = 799 + 32 * wl;  // t0 at ivLoB
#define QLD0(k) q##k = po[dbase(t0p + 2 - (k)) + r];
    REP33(QLD0)
  }

#pragma unroll 1
  for (int iv = 0; iv < NIV; ++iv) {
    if (iv >= ivLoB && iv <= ivHiB) {
      const int t0 = 1247 - 32 * wl - 32 * iv;  // scalar
      const float* ErB = &Ering[wb][wl][(t0 - 30) & 127];
      const uint32_t* PrB = &Pring[wb][wl][(t0 - 30) & 127];
#define DECLRE(k) float rE##k = ErB[32 - (k)]; uint32_t rP##k = PrB[32 - (k)];
      LIST1_32(DECLRE)
      // issue next-interval p loads (stay in flight across BAR)
      if (iv < ivHiB) {
        const int t0n = t0 - 32;
#define QLDN(k) qn##k = po[dbase(t0n + 2 - (k)) + r];
        REP33(QLDN)
      }

#define BSTEP(m, k) { \
    const int t = t0 - (m); \
    const float reb = reaP; \
    const float rea = dpp_shl1_f(ea, rE##k); \
    const uint32_t rq2 = rqP; \
    const uint32_t rq1 = dpp_shl1_u(q##k, rP##k); \
    const bool vd = (unsigned)(t - r - 1) < 512u; \
    const bool rt = (unsigned)(t - r) < 512u; \
    const float pd = (float)(rq2 & 0xffffu) * inv16; \
    const float pu = (float)(rq1 >> 16) * inv16; \
    const float pl = 1.0f - (float)(q##k & 0xffffu) * inv16 - (float)(q##k >> 16) * inv16; \
    float n = (rless ? rea * pu : 0.0f) + ((rless && rt) ? reb * pd : 0.0f) + (rt ? ea * pl : 0.0f); \
    n = vd ? n : 0.0f; \
    if (vd) ews[dbase(t) + r] = n; \
    if (wgt0 && lane0) { const int sl = t & 127; Ering[wb][wl - 1][sl] = n; Ering[wb][wl - 1][sl + 128] = n; } \
    ea = n; reaP = rea; rqP = rq1; \
  }
      BSTEP(0, 1)  BSTEP(1, 2)  BSTEP(2, 3)  BSTEP(3, 4)  BSTEP(4, 5)  BSTEP(5, 6)  BSTEP(6, 7)  BSTEP(7, 8)
      BSTEP(8, 9)  BSTEP(9, 10) BSTEP(10, 11) BSTEP(11, 12) BSTEP(12, 13) BSTEP(13, 14) BSTEP(14, 15) BSTEP(15, 16)
      BSTEP(16, 17) BSTEP(17, 18) BSTEP(18, 19) BSTEP(19, 20) BSTEP(20, 21) BSTEP(21, 22) BSTEP(22, 23) BSTEP(23, 24)
      BSTEP(24, 25) BSTEP(25, 26) BSTEP(26, 27) BSTEP(27, 28) BSTEP(28, 29) BSTEP(29, 30) BSTEP(30, 31) BSTEP(31, 32)

      // publish own p-packs for downstream reader (row = this wave's lane0 row)
      if (wgt0 && lane0) {
#define PWR(k) { const int sl = (t0 + 2 - (k)) & 127; Pring[wb][wl - 1][sl] = q##k; Pring[wb][wl - 1][sl + 128] = q##k; }
        REP33(PWR)
      }
      // roll pipelined q
      if (iv < ivHiB) {
#define QMV(k) q##k = qn##k;
        REP33(QMV)
      }
    }
    BAR();
  }
}

// ---------------------------------------------------------------------------
// K5: transpose diag-major E (ws) -> row-major out. 64x64 cell tiles.
// ---------------------------------------------------------------------------
__global__ __launch_bounds__(256) void k_tr(const float* __restrict__ ews, float* __restrict__ out) {
  const int blk = blockIdx.x;
  const int b = blk >> 6, ti = (blk >> 3) & 7, tj = blk & 7;
  const float* src = ews + (size_t)b * NCELL;
  float* dst = out + (size_t)b * NCELL;
  __shared__ float tile[64][68];
  const int i0 = ti * 64, j0 = tj * 64;
  const int t = threadIdx.x;
  const int sub = t >> 6, lane = t & 63;
  for (int k = sub; k < 127; k += 4) {
    const int d = i0 + j0 + 2 + k;
    const int ilo_t = max(i0 + 1, d - (j0 + 64));
    const int ihi_t = min(i0 + 64, d - (j0 + 1));
    const int i = ilo_t + lane;
    if (i <= ihi_t) {
      const int lo = (d > 513) ? d - 512 : 1;
      tile[i - 1 - i0][d - i - 1 - j0] = src[offd(d) - lo + i];
    }
  }
  __syncthreads();
  const int rr = t >> 2, q = (t & 3) * 16;
  float4* drow = (float4*)&dst[(size_t)(i0 + rr) * 512 + j0 + q];
  const float* srow = &tile[rr][q];
  drow[0] = *(const float4*)&srow[0];
  drow[1] = *(const float4*)&srow[4];
  drow[2] = *(const float4*)&srow[8];
  drow[3] = *(const float4*)&srow[12];
}

// ---------------------------------------------------------------------------
extern "C" void kernel_launch(void* const* d_in, const int* in_sizes, int n_in,
                              void* d_out, int out_size, void* d_ws, size_t ws_size,
                              hipStream_t stream) {
  const int* x = (const int*)d_in[0];
  const int* y = (const int*)d_in[1];
  const float* We = (const float*)d_in[2];
  const float* Wp = (const float*)d_in[3];
  const float* bp = (const float*)d_in[4];
  const float* Wg = (const float*)d_in[5];
  const float* bg = (const float*)d_in[6];
  float* out = (float*)d_out;

  float* ws = (float*)d_ws;
  float* T = ws;              // 22*512 floats
  float* G = ws + 11264;      // 814 (22x37 padded)
  float* u = G + 814;         // 22
  float* v = u + 22;          // 22
  float* A = v + 22;          // 16
  float* ews = (float*)((char*)d_ws + (1 << 20));  // 16 MiB diag-major E

  k_T<<<22, 512, 0, stream>>>(We, Wp, bp, T);
  k_G<<<1, 512, 0, stream>>>(T, Wg, G, u, v);
  k_A<<<16, 256, 0, stream>>>(x, y, u, v, bg, A);
  k_nw<<<8, 1024, 0, stream>>>(x, y, G, A, (uint32_t*)d_out, ews);
  k_tr<<<16 * 64, 256, 0, stream>>>(ews, out);
}

// Round 13
// 481.285 us; speedup vs baseline: 1.5847x; 1.5847x over previous
//
#include <hip/hip_runtime.h>
#include <stdint.h>

#define NEGF (-1.0e8f)
#define NCELL (512 * 512)
#define INVLN2 1.4426950408889634f
#define NIV 71  // intervals of 16 diagonals; skew 16/wave

// raw barrier: LDS ordering only (never drains vmcnt -> global ops stay in flight)
#define BAR() asm volatile("s_waitcnt lgkmcnt(0)\n\ts_barrier" ::: "memory")

#define REP16(X) X(0) X(1) X(2) X(3) X(4) X(5) X(6) X(7) X(8) X(9) X(10) X(11) X(12) X(13) X(14) X(15)
#define REP18(X) REP16(X) X(16) X(17)

__device__ __forceinline__ float exp2f_(float x) {
#if __has_builtin(__builtin_amdgcn_exp2f)
  return __builtin_amdgcn_exp2f(x);
#else
  return exp2f(x);
#endif
}
__device__ __forceinline__ float log2f_(float x) {
#if __has_builtin(__builtin_amdgcn_logf)
  return __builtin_amdgcn_logf(x);
#else
  return log2f(x);
#endif
}
__device__ __forceinline__ uint32_t pknorm16(float a, float b) {
#if __has_builtin(__builtin_amdgcn_cvt_pknorm_u16)
  typedef unsigned short u2v __attribute__((ext_vector_type(2)));
  union { u2v v; uint32_t u; } cv;
  cv.v = __builtin_amdgcn_cvt_pknorm_u16(a, b);
  return cv.u;
#else
  uint32_t pa = (uint32_t)(a * 65535.0f + 0.5f);
  uint32_t pb = (uint32_t)(b * 65535.0f + 0.5f);
  return pa | (pb << 16);
#endif
}

// DPP wave shifts: 0x138 wave_shr:1 (lane l <- l-1, lane0 <- old), 0x130 wave_shl:1 (lane l <- l+1, lane63 <- old)
__device__ __forceinline__ float dpp_shr1_f(float src, float old0) {
  return __int_as_float(__builtin_amdgcn_update_dpp(
      __float_as_int(old0), __float_as_int(src), 0x138, 0xF, 0xF, false));
}
__device__ __forceinline__ float dpp_shl1_f(float src, float old63) {
  return __int_as_float(__builtin_amdgcn_update_dpp(
      __float_as_int(old63), __float_as_int(src), 0x130, 0xF, 0xF, false));
}
__device__ __forceinline__ uint32_t dpp_shl1_u(uint32_t src, uint32_t old63) {
  return (uint32_t)__builtin_amdgcn_update_dpp((int)old63, (int)src, 0x130, 0xF, 0xF, false);
}

// offset of diagonal d; lo(d)=max(1,d-512)
__device__ __forceinline__ int offd(int d) {
  return (d <= 513) ? (((d - 2) * (d - 1)) >> 1)
                    : (NCELL - (((1025 - d) * (1026 - d)) >> 1));
}
__device__ __forceinline__ int dbase(int d) {
  const int lo = (d > 513) ? d - 512 : 1;
  return offd(d) - lo;
}

// forward softmax-LSE cell (base-2 domain)
__device__ __forceinline__ void fcell(float& nv, uint32_t& pk, float dg, float up0,
                                      float lf0, float th, float A2) {
  float up = up0 + A2, lf = lf0 + A2;
  float mx = fmaxf(fmaxf(dg, up), lf);
  float ed = exp2f_(dg - mx), eu = exp2f_(up - mx), el = exp2f_(lf - mx);
  float s = ed + eu + el;
  nv = th + mx + log2f_(s);
  float rs = __builtin_amdgcn_rcpf(s);
  pk = pknorm16(ed * rs, eu * rs);
}

// ---------------------------------------------------------------------------
// K1: T[22][512] = W_embed @ W_proj + b_proj
// ---------------------------------------------------------------------------
__global__ void k_T(const float* __restrict__ We, const float* __restrict__ Wp,
                    const float* __restrict__ bp, float* __restrict__ T) {
  int a = blockIdx.x, c = threadIdx.x;
  __shared__ float e[512];
  e[c] = We[a * 512 + c];
  __syncthreads();
  float acc = bp[c];
#pragma unroll 8
  for (int k = 0; k < 512; ++k) acc = fmaf(e[k], Wp[k * 512 + c], acc);
  T[a * 512 + c] = acc;
}

// ---------------------------------------------------------------------------
// K2: G2[a][a2] (stride 37 for LDS bank spread) = (T T^T)/ln2 ; u,v gap LUTs
// ---------------------------------------------------------------------------
__global__ void k_G(const float* __restrict__ T, const float* __restrict__ Wg,
                    float* __restrict__ G, float* __restrict__ u, float* __restrict__ v) {
  __shared__ float Ts[22 * 516];
  for (int k = threadIdx.x; k < 22 * 512; k += 512) {
    int a = k >> 9, c = k & 511;
    Ts[a * 516 + c] = T[k];
  }
  __syncthreads();
  for (int idx = threadIdx.x; idx < 528; idx += 512) {
    float s = 0.f;
    if (idx < 484) {
      int a = idx / 22, a2 = idx - 22 * a;
      const float* pa = &Ts[a * 516];
      const float* pb = &Ts[a2 * 516];
      for (int c = 0; c < 512; ++c) s = fmaf(pa[c], pb[c], s);
      G[a * 37 + a2] = s * INVLN2;  // padded row stride 37
    } else if (idx < 506) {
      int a = idx - 484;
      const float* pa = &Ts[a * 516];
      for (int c = 0; c < 512; ++c) s = fmaf(pa[c], Wg[c], s);
      u[a] = s;
    } else {
      int a = idx - 506;
      const float* pa = &Ts[a * 516];
      for (int c = 0; c < 512; ++c) s = fmaf(pa[c], Wg[512 + c], s);
      v[a] = s;
    }
  }
}

// ---------------------------------------------------------------------------
// K3: A2[b]
// ---------------------------------------------------------------------------
__global__ void k_A(const int* __restrict__ x, const int* __restrict__ y,
                    const float* __restrict__ u, const float* __restrict__ v,
                    const float* __restrict__ bg, float* __restrict__ A) {
  int b = blockIdx.x, t = threadIdx.x;
  const int* xb = x + b * 512;
  const int* yb = y + b * 512;
  float s = u[xb[t]] + u[xb[t + 256]] + v[yb[t]] + v[yb[t + 256]];
  for (int o = 32; o > 0; o >>= 1) s += __shfl_down(s, o, 64);
  __shared__ float w[4];
  if ((t & 63) == 0) w[t >> 6] = s;
  __syncthreads();
  if (t == 0) A[b] = ((w[0] + w[1] + w[2] + w[3]) * (1.0f / 512.0f) + bg[0]) * INVLN2;
}

// ---------------------------------------------------------------------------
// K4: skewed 8-wave pipeline DP, KD=16, gating, LDS-instruction-minimized:
//     ring reads via 5x ds_read_b128, ring writes batched (stash->b128x4 x2).
// ---------------------------------------------------------------------------
__global__ __launch_bounds__(512) void k_nw(const int* __restrict__ x, const int* __restrict__ y,
                                            const float* __restrict__ G,
                                            const float* __restrict__ Aarr,
                                            uint32_t* __restrict__ po,
                                            float* __restrict__ ews) {
  const int tid = threadIdx.x;
  const int wl = __builtin_amdgcn_readfirstlane(tid) >> 6;  // wave id, forced SGPR
  const int lane = tid & 63;
  __shared__ float Gl[814];       // 22 x 37
  __shared__ int ysPad[1856];     // zeros [0,640), ys [640,1152), zeros [1152,1856)
  __shared__ float Vring[8][256];     // slot(d)=(d-2)&127, copy at +128
  __shared__ float Ering[8][256];     // slot(d)=d&127, copy at +128
  __shared__ uint32_t Pring[8][256];  // slot(d)=d&127, copy at +128

  const int b = blockIdx.x;
  const int* xbp = x + b * 512;
  const int* ybp = y + b * 512;
  for (int k = tid; k < 640; k += 512) ysPad[k] = 0;
  for (int k = 1152 + tid; k < 1856; k += 512) ysPad[k] = 0;
  ysPad[640 + tid] = ybp[tid];
  for (int k = tid; k < 814; k += 512) Gl[k] = G[k];
  for (int k = tid; k < 2048; k += 512) {
    ((float*)Vring)[k] = NEGF;
    ((float*)Ering)[k] = 0.0f;
    ((uint32_t*)Pring)[k] = 0u;
  }
  const float A2 = Aarr[b];
  const int r = 64 * wl + lane + 1;
  const int xr = xbp[r - 1] * 37;
  const bool lane0 = (lane == 0), lane63 = (lane == 63);
  const bool wgt0 = (wl > 0), wlt7 = (wl < 7);
  const bool rless = (r < 512);
  po += (size_t)b * NCELL;
  ews += (size_t)b * NCELL;
  __syncthreads();

  // ================= forward =================
  const int ivLoF = 5 * wl;
  const int ivHiF = (5 * wl + 35 < NIV - 1) ? 5 * wl + 35 : NIV - 1;
  const int dnP0 = 2 + 64 * wl;  // dn0 at ivLoF

#define DECLTH(m) float th##m;
  REP16(DECLTH)
#define DECLYA(m) int ya##m;
  REP16(DECLYA)
#define PROTH(m) { const int ix = (dnP0 + (m)) + 639 - r; th##m = Gl[xr + ysPad[ix]]; }
  REP16(PROTH)

  float va = NEGF, rupP = NEGF;
#pragma unroll 1
  for (int iv = 0; iv < NIV; ++iv) {
    if (iv >= ivLoF && iv <= ivHiF) {
      const int dn0 = 2 - 16 * wl + 16 * iv;  // scalar
      const int s0 = (dn0 - 2) & 127;        // multiple of 16
      const int A = (s0 == 0) ? 124 : s0 - 4;
      const float* VrB = &Vring[wl][A];
      const float4 F0 = *(const float4*)&VrB[0];
      const float4 F1 = *(const float4*)&VrB[4];
      const float4 F2 = *(const float4*)&VrB[8];
      const float4 F3 = *(const float4*)&VrB[12];
      const float4 F4 = *(const float4*)&VrB[16];
      // batch-load next interval's ys into registers (stride-1, conflict-light)
      const int iya = dn0 + 655 - r;
#define LYA(m) ya##m = ysPad[iya + (m)];
      REP16(LYA)
#define DECLST(m) float st##m;
      REP16(DECLST)

#define FSTEP(m, RVC) { \
    const int dn = dn0 + (m); \
    float rdg = rupP; \
    if ((m) == 0 && wl == 0 && iv == 0) rdg = lane0 ? 0.0f : rdg; /* V[0,0]=0 corner */ \
    const float rup = dpp_shr1_f(va, (RVC)); \
    float nv; uint32_t pk; \
    fcell(nv, pk, rdg, rup, va, th##m, A2); \
    const bool vv = (unsigned)(dn - r - 1) < 512u; \
    nv = vv ? nv : NEGF; \
    if (vv) po[dbase(dn) + r] = pk; \
    st##m = nv; \
    th##m = Gl[xr + ya##m]; \
    va = nv; rupP = rup; \
  }
      FSTEP(0, F0.w)  FSTEP(1, F1.x)  FSTEP(2, F1.y)  FSTEP(3, F1.z)  FSTEP(4, F1.w)
      FSTEP(5, F2.x)  FSTEP(6, F2.y)  FSTEP(7, F2.z)  FSTEP(8, F2.w)
      FSTEP(9, F3.x)  FSTEP(10, F3.y) FSTEP(11, F3.z) FSTEP(12, F3.w)
      FSTEP(13, F4.x) FSTEP(14, F4.y) FSTEP(15, F4.z)

      if (wlt7 && lane63) {  // batched boundary publish: diags [dn0, dn0+15]
        float* Wp_ = &Vring[wl + 1][s0];
        *(float4*)&Wp_[0] = make_float4(st0, st1, st2, st3);
        *(float4*)&Wp_[4] = make_float4(st4, st5, st6, st7);
        *(float4*)&Wp_[8] = make_float4(st8, st9, st10, st11);
        *(float4*)&Wp_[12] = make_float4(st12, st13, st14, st15);
        *(float4*)&Wp_[128] = make_float4(st0, st1, st2, st3);
        *(float4*)&Wp_[132] = make_float4(st4, st5, st6, st7);
        *(float4*)&Wp_[136] = make_float4(st8, st9, st10, st11);
        *(float4*)&Wp_[140] = make_float4(st12, st13, st14, st15);
      }
    }
    BAR();
  }

  // ================= transition: drain p stores once =================
  asm volatile("s_waitcnt vmcnt(0)" ::: "memory");
  __threadfence_block();
  __syncthreads();

  // ================= backward =================
  const float inv16 = 1.0f / 65535.0f;
  const bool w7 = (wl == 7);
  const int ivLoB = (34 - 5 * wl > 0) ? 34 - 5 * wl : 0;
  const int ivHiB = 70 - 5 * wl;
  float ea = (w7 && lane63) ? 1.0f : 0.0f;
  float reaP = 0.0f;
  uint32_t rqP = 0u;
  if (w7 && lane63) ews[NCELL - 1] = 1.0f;  // E(512,512) seed (diag 1024)

#define DECLQ(k) uint32_t q##k, qn##k;
  REP18(DECLQ)
  {
    const int t0p = 1135 - 16 * wl - 16 * ivLoB;
#define QLD0(k) q##k = po[dbase(t0p + 2 - (k)) + r];
    REP18(QLD0)
  }

#pragma unroll 1
  for (int iv = 0; iv < NIV; ++iv) {
    if (iv >= ivLoB && iv <= ivHiB) {
      const int t0 = 1135 - 16 * wl - 16 * iv;  // scalar; t0 % 16 == 15
      const int eb = (t0 - 15) & 127;           // multiple of 16
      const float* ErB = &Ering[wl][eb];
      const uint32_t* PrB = &Pring[wl][eb];
      const float4 G0 = *(const float4*)&ErB[0];
      const float4 G1 = *(const float4*)&ErB[4];
      const float4 G2 = *(const float4*)&ErB[8];
      const float4 G3 = *(const float4*)&ErB[12];
      const float4 G4 = *(const float4*)&ErB[16];
      const uint4 P0 = *(const uint4*)&PrB[0];
      const uint4 P1 = *(const uint4*)&PrB[4];
      const uint4 P2 = *(const uint4*)&PrB[8];
      const uint4 P3 = *(const uint4*)&PrB[12];
      const uint4 P4 = *(const uint4*)&PrB[16];
      // issue next-interval p loads (stay in flight across BAR)
      if (iv < ivHiB) {
        const int t0n = t0 - 16;
#define QLDN(k) qn##k = po[dbase(t0n + 2 - (k)) + r];
        REP18(QLDN)
      }
#define DECLSE(m) float stE##m;
      REP16(DECLSE)

#define BSTEP(m, QK, REC, RPC) { \
    const int t = t0 - (m); \
    const float reb = reaP; \
    const float rea = dpp_shl1_f(ea, (REC)); \
    const uint32_t rq2 = rqP; \
    const uint32_t rq1 = dpp_shl1_u((QK), (RPC)); \
    const bool vd = (unsigned)(t - r - 1) < 512u; \
    const bool rt = (unsigned)(t - r) < 512u; \
    const float pd = (float)(rq2 & 0xffffu) * inv16; \
    const float pu = (float)(rq1 >> 16) * inv16; \
    const float pl = 1.0f - (float)((QK) & 0xffffu) * inv16 - (float)((QK) >> 16) * inv16; \
    float n = (rless ? rea * pu : 0.0f) + ((rless && rt) ? reb * pd : 0.0f) + (rt ? ea * pl : 0.0f); \
    n = vd ? n : 0.0f; \
    if (vd) ews[dbase(t) + r] = n; \
    stE##m = n; \
    ea = n; reaP = rea; rqP = rq1; \
  }
      BSTEP(0, q1, G4.x, P4.x)  BSTEP(1, q2, G3.w, P3.w)  BSTEP(2, q3, G3.z, P3.z)
      BSTEP(3, q4, G3.y, P3.y)  BSTEP(4, q5, G3.x, P3.x)  BSTEP(5, q6, G2.w, P2.w)
      BSTEP(6, q7, G2.z, P2.z)  BSTEP(7, q8, G2.y, P2.y)  BSTEP(8, q9, G2.x, P2.x)
      BSTEP(9, q10, G1.w, P1.w) BSTEP(10, q11, G1.z, P1.z) BSTEP(11, q12, G1.y, P1.y)
      BSTEP(12, q13, G1.x, P1.x) BSTEP(13, q14, G0.w, P0.w) BSTEP(14, q15, G0.z, P0.z)
      BSTEP(15, q16, G0.y, P0.y)

      if (wgt0 && lane0) {  // batched publish: E diags [t0-15,t0], P diags [t0-15,t0+2] (+pad)
        float* We_ = &Ering[wl - 1][eb];
        *(float4*)&We_[0] = make_float4(stE15, stE14, stE13, stE12);
        *(float4*)&We_[4] = make_float4(stE11, stE10, stE9, stE8);
        *(float4*)&We_[8] = make_float4(stE7, stE6, stE5, stE4);
        *(float4*)&We_[12] = make_float4(stE3, stE2, stE1, stE0);
        *(float4*)&We_[128] = make_float4(stE15, stE14, stE13, stE12);
        *(float4*)&We_[132] = make_float4(stE11, stE10, stE9, stE8);
        *(float4*)&We_[136] = make_float4(stE7, stE6, stE5, stE4);
        *(float4*)&We_[140] = make_float4(stE3, stE2, stE1, stE0);
        uint32_t* Pw_ = &Pring[wl - 1][eb];
        *(uint4*)&Pw_[0] = make_uint4(q17, q16, q15, q14);
        *(uint4*)&Pw_[4] = make_uint4(q13, q12, q11, q10);
        *(uint4*)&Pw_[8] = make_uint4(q9, q8, q7, q6);
        *(uint4*)&Pw_[12] = make_uint4(q5, q4, q3, q2);
        *(uint4*)&Pw_[16] = make_uint4(q1, q0, q0, q0);
        *(uint4*)&Pw_[128] = make_uint4(q17, q16, q15, q14);
        *(uint4*)&Pw_[132] = make_uint4(q13, q12, q11, q10);
        *(uint4*)&Pw_[136] = make_uint4(q9, q8, q7, q6);
        *(uint4*)&Pw_[140] = make_uint4(q5, q4, q3, q2);
        *(uint4*)&Pw_[144] = make_uint4(q1, q0, q0, q0);
      }
      // roll pipelined q
      if (iv < ivHiB) {
#define QMV(k) q##k = qn##k;
        REP18(QMV)
      }
    }
    BAR();
  }
}

// ---------------------------------------------------------------------------
// K5: transpose diag-major E (ws) -> row-major out. 64x64 cell tiles.
// ---------------------------------------------------------------------------
__global__ __launch_bounds__(256) void k_tr(const float* __restrict__ ews, float* __restrict__ out) {
  const int blk = blockIdx.x;
  const int b = blk >> 6, ti = (blk >> 3) & 7, tj = blk & 7;
  const float* src = ews + (size_t)b * NCELL;
  float* dst = out + (size_t)b * NCELL;
  __shared__ float tile[64][68];
  const int i0 = ti * 64, j0 = tj * 64;
  const int t = threadIdx.x;
  const int sub = t >> 6, lane = t & 63;
  for (int k = sub; k < 127; k += 4) {
    const int d = i0 + j0 + 2 + k;
    const int ilo_t = max(i0 + 1, d - (j0 + 64));
    const int ihi_t = min(i0 + 64, d - (j0 + 1));
    const int i = ilo_t + lane;
    if (i <= ihi_t) {
      const int lo = (d > 513) ? d - 512 : 1;
      tile[i - 1 - i0][d - i - 1 - j0] = src[offd(d) - lo + i];
    }
  }
  __syncthreads();
  const int rr = t >> 2, q = (t & 3) * 16;
  float4* drow = (float4*)&dst[(size_t)(i0 + rr) * 512 + j0 + q];
  const float* srow = &tile[rr][q];
  drow[0] = *(const float4*)&srow[0];
  drow[1] = *(const float4*)&srow[4];
  drow[2] = *(const float4*)&srow[8];
  drow[3] = *(const float4*)&srow[12];
}

// ---------------------------------------------------------------------------
extern "C" void kernel_launch(void* const* d_in, const int* in_sizes, int n_in,
                              void* d_out, int out_size, void* d_ws, size_t ws_size,
                              hipStream_t stream) {
  const int* x = (const int*)d_in[0];
  const int* y = (const int*)d_in[1];
  const float* We = (const float*)d_in[2];
  const float* Wp = (const float*)d_in[3];
  const float* bp = (const float*)d_in[4];
  const float* Wg = (const float*)d_in[5];
  const float* bg = (const float*)d_in[6];
  float* out = (float*)d_out;

  float* ws = (float*)d_ws;
  float* T = ws;              // 22*512 floats
  float* G = ws + 11264;      // 814 (22x37 padded)
  float* u = G + 814;         // 22
  float* v = u + 22;          // 22
  float* A = v + 22;          // 16
  float* ews = (float*)((char*)d_ws + (1 << 20));  // 16 MiB diag-major E

  k_T<<<22, 512, 0, stream>>>(We, Wp, bp, T);
  k_G<<<1, 512, 0, stream>>>(T, Wg, G, u, v);
  k_A<<<16, 256, 0, stream>>>(x, y, u, v, bg, A);
  k_nw<<<16, 512, 0, stream>>>(x, y, G, A, (uint32_t*)d_out, ews);
  k_tr<<<16 * 64, 256, 0, stream>>>(ews, out);
}